// Round 6
// baseline (4636.481 us; speedup 1.0000x reference)
//
#include <hip/hip_runtime.h>
#include <hip/hip_fp16.h>
#include <hip/hip_cooperative_groups.h>

namespace cg = cooperative_groups;

#define B_N 65536
#define K_N 256
#define D_N 128
#define N_ITER 50
#define NSHARD 8
#define BUFSTRIDE (NSHARD * K_N)  // 2048 floats per colsum buffer (8 shards x 256)
#define NBLK 1024
#define BAR_SH 16
#define BLK_PER_SH (NBLK / BAR_SH)  // 64
#define EPOCH_IDX 17
#define FLAG_IDX 32

constexpr float MU_EPS = 1.0f / 65536.0f + 1e-8f;  // exp(log_mu)
constexpr float NU_EPS = 1.0f / 256.0f + 1e-8f;    // exp(log_nu)
constexpr float KSCALE = 8192.0f;                  // keeps fp16 kappa in normal range
constexpr float INV_KSCALE = 1.0f / 8192.0f;
constexpr float NUKS = NU_EPS * KSCALE;
constexpr float MUKS = MU_EPS * KSCALE;

__device__ __forceinline__ float wave_sum(float v) {
#pragma unroll
    for (int m = 1; m < 64; m <<= 1) v += __shfl_xor(v, m, 64);
    return v;
}
__device__ __forceinline__ float wave_max(float v) {
#pragma unroll
    for (int m = 1; m < 64; m <<= 1) v = fmaxf(v, __shfl_xor(v, m, 64));
    return v;
}

// ---------------------------------------------------------------------------
// Blocks 0..255: L2-normalize prototype rows. Block 256: init colsum buffers
// (3-buffer rotation; buf2/shard0 = NUKS so iteration 0 sees exp(v)=1), zero
// barrier counters + success flag (monotonic within one launch -> re-zero
// every call), and zero d_out (harness poisons with 0xAA).
// ---------------------------------------------------------------------------
__global__ __launch_bounds__(64) void proto_norm_init(
        const float* __restrict__ proto, float* __restrict__ yn,
        float* __restrict__ csbuf, unsigned* __restrict__ bar,
        float* __restrict__ out) {
    const int blk = blockIdx.x;
    const int lane = threadIdx.x;
    if (blk < 256) {
        float2 p = *(const float2*)&proto[blk * 128 + lane * 2];
        float ss = wave_sum(p.x * p.x + p.y * p.y);
        float inv = 1.0f / fmaxf(sqrtf(ss), 1e-12f);
        *(float2*)&yn[blk * 128 + lane * 2] = make_float2(p.x * inv, p.y * inv);
    } else {
        for (int i = lane; i < 3 * BUFSTRIDE; i += 64)
            csbuf[i] = (i >= 2 * BUFSTRIDE && i < 2 * BUFSTRIDE + K_N) ? NUKS : 0.0f;
        bar[lane] = 0u;  // covers shard counters, master, epoch, FLAG_IDX
        if (lane == 0) out[0] = 0.0f;
    }
}

// rn[i] = 1 / max(||x_i||, 1e-12)  (one wave per row, 16 rows per wave)
__global__ __launch_bounds__(256) void row_norm(const float* __restrict__ x,
                                                float* __restrict__ rn) {
    const int tid = threadIdx.x;
    const int wave = tid >> 6, lane = tid & 63;
    const int row0 = blockIdx.x * 64 + wave * 16;
    for (int r = 0; r < 16; r++) {
        const int row = row0 + r;
        float2 p = *(const float2*)&x[(size_t)row * 128 + lane * 2];
        float ss = wave_sum(p.x * p.x + p.y * p.y);
        if (lane == 0) rn[row] = 1.0f / fmaxf(sqrtf(ss), 1e-12f);
    }
}

// ---------------------------------------------------------------------------
// C[i,k] = 1 - (x_i . yn_k) * rn_i  ;  kappa = KSCALE*(exp(-C/eps)+1e-8) fp16
// C is NOT stored: finalize recovers it as -eps*ln(kappa/KSCALE - 1e-8).
// ---------------------------------------------------------------------------
__global__ __launch_bounds__(256) void gemm_kc(
        const float* __restrict__ x, const float* __restrict__ yn,
        const float* __restrict__ rn, __half* __restrict__ kappa) {
    __shared__ __align__(16) float as[16][68];  // transposed tiles: [kk][row]
    __shared__ __align__(16) float bs[16][68];
    const int tid = threadIdx.x;
    const int tx = tid & 15, ty = tid >> 4;
    const int row0 = blockIdx.x * 64, col0 = blockIdx.y * 64;
    const int lr = tid >> 2, lq = tid & 3;
    float acc[4][4] = {};
    const float rnv = rn[row0 + lr];
    for (int d0 = 0; d0 < 128; d0 += 16) {
        float4 av = *(const float4*)&x[(size_t)(row0 + lr) * 128 + d0 + lq * 4];
        float4 bv = *(const float4*)&yn[(col0 + lr) * 128 + d0 + lq * 4];
        as[lq * 4 + 0][lr] = av.x * rnv;
        as[lq * 4 + 1][lr] = av.y * rnv;
        as[lq * 4 + 2][lr] = av.z * rnv;
        as[lq * 4 + 3][lr] = av.w * rnv;
        bs[lq * 4 + 0][lr] = bv.x;
        bs[lq * 4 + 1][lr] = bv.y;
        bs[lq * 4 + 2][lr] = bv.z;
        bs[lq * 4 + 3][lr] = bv.w;
        __syncthreads();
#pragma unroll
        for (int kk = 0; kk < 16; kk++) {
            float4 a4 = *(const float4*)&as[kk][ty * 4];
            float4 b4 = *(const float4*)&bs[kk][tx * 4];
            float aa[4] = {a4.x, a4.y, a4.z, a4.w};
            float bb[4] = {b4.x, b4.y, b4.z, b4.w};
#pragma unroll
            for (int i = 0; i < 4; i++)
#pragma unroll
                for (int j = 0; j < 4; j++) acc[i][j] = fmaf(aa[i], bb[j], acc[i][j]);
        }
        __syncthreads();
    }
    union H4 { __half h[4]; uint2 u; };
#pragma unroll
    for (int i = 0; i < 4; i++) {
        const int row = row0 + ty * 4 + i;
        H4 hk;
#pragma unroll
        for (int j = 0; j < 4; j++) {
            float Cv = 1.0f - acc[i][j];
            hk.h[j] = __float2half(KSCALE * (__expf(-10.0f * Cv) + 1e-8f));
        }
        *(uint2*)&kappa[(size_t)row * 256 + col0 + tx * 4] = hk.u;
    }
}

// ---------------------------------------------------------------------------
// 2-level sharded grid barrier, monotonic counters (zeroed every launch).
// All RMWs ACQ_REL at agent scope -> full happens-before chain to the
// epoch-flag acquire spin.
// ---------------------------------------------------------------------------
__device__ __forceinline__ void grid_barrier(unsigned* bar, int t, int blk, int tid) {
    __syncthreads();  // drains this block's vmem (incl. its colsum atomics)
    if (tid == 0) {
        unsigned old = __hip_atomic_fetch_add(&bar[blk & (BAR_SH - 1)], 1u,
                                              __ATOMIC_ACQ_REL, __HIP_MEMORY_SCOPE_AGENT);
        if (old == (unsigned)((t + 1) * BLK_PER_SH - 1)) {
            unsigned mo = __hip_atomic_fetch_add(&bar[BAR_SH], 1u,
                                                 __ATOMIC_ACQ_REL, __HIP_MEMORY_SCOPE_AGENT);
            if (mo == (unsigned)((t + 1) * BAR_SH - 1))
                __hip_atomic_store(&bar[EPOCH_IDX], (unsigned)(t + 1),
                                   __ATOMIC_RELEASE, __HIP_MEMORY_SCOPE_AGENT);
        }
        while (__hip_atomic_load(&bar[EPOCH_IDX], __ATOMIC_ACQUIRE,
                                 __HIP_MEMORY_SCOPE_AGENT) < (unsigned)(t + 1))
            __builtin_amdgcn_s_sleep(2);
    }
    __syncthreads();
}

// ---------------------------------------------------------------------------
// ALL 50 Sinkhorn iterations in ONE cooperative launch. Launch shape matches
// round 1's PROVEN-launchable coop kernel: 1024 blocks, launch_bounds(256,4),
// cg::this_grid() referenced (marks the kernel cooperative to the runtime —
// rounds 4/5 omitted this and the coop launch silently failed). Kappa is
// re-read from L2 each iteration (low VGPR -> large occupancy margin).
// Body = round-3's proven sinkhorn_step. Sets bar[FLAG_IDX]=1 on completion;
// the gated fallback steps below skip themselves when they see it.
// ---------------------------------------------------------------------------
__global__ __launch_bounds__(256, 4) void sinkhorn_persist(
        const __half* __restrict__ kappa, float* __restrict__ csbuf,
        float* __restrict__ aexp, unsigned* __restrict__ bar) {
    cg::grid_group grid = cg::this_grid();  // cooperative anchor
    __shared__ __align__(16) float ev_lds[256];
    __shared__ float cs_lds[4 * 273];  // [wave][chunk*17 + j] — stride-17, conflict-free
    const int blk = blockIdx.x, tid = threadIdx.x;
    const int w = tid >> 6, lane = tid & 63;
    const int g = lane >> 4, c = lane & 15;
    const int row_base = blk * 64 + w * 16 + g;  // + rg*4, rg in 0..3
    const uint4* kb = (const uint4*)kappa;       // 8 halves per uint4; row = 32 uint4
    for (int t = 0; t < N_ITER; t++) {
        const int p_read = (t + 2) % 3, p_acc = t % 3, p_zero = (t + 1) % 3;
        {   // ev_k = NUKS / colsum_k  (thread tid owns column tid)
            const float* cb = csbuf + p_read * BUFSTRIDE;
            float cs = 0.0f;
#pragma unroll
            for (int s = 0; s < NSHARD; s++)
                cs += __hip_atomic_load(&cb[s * 256 + tid], __ATOMIC_RELAXED,
                                        __HIP_MEMORY_SCOPE_AGENT);
            ev_lds[tid] = NUKS * __builtin_amdgcn_rcpf(cs);
        }
        if (blk < NSHARD)
            __hip_atomic_store(&csbuf[p_zero * BUFSTRIDE + blk * 256 + tid], 0.0f,
                               __ATOMIC_RELAXED, __HIP_MEMORY_SCOPE_AGENT);
        __syncthreads();
        float e[16];
        {
            float4 e0 = *(const float4*)&ev_lds[c * 16 + 0];
            float4 e1 = *(const float4*)&ev_lds[c * 16 + 4];
            float4 e2 = *(const float4*)&ev_lds[c * 16 + 8];
            float4 e3 = *(const float4*)&ev_lds[c * 16 + 12];
            e[0] = e0.x; e[1] = e0.y; e[2] = e0.z; e[3] = e0.w;
            e[4] = e1.x; e[5] = e1.y; e[6] = e1.z; e[7] = e1.w;
            e[8] = e2.x; e[9] = e2.y; e[10] = e2.z; e[11] = e2.w;
            e[12] = e3.x; e[13] = e3.y; e[14] = e3.z; e[15] = e3.w;
        }
        uint4 kv[4][2];
#pragma unroll
        for (int rg = 0; rg < 4; rg++) {
            const size_t base = (size_t)(row_base + rg * 4) * 32 + c * 2;
            kv[rg][0] = kb[base];
            kv[rg][1] = kb[base + 1];
        }
        float acc[16];
#pragma unroll
        for (int j = 0; j < 16; j++) acc[j] = 0.0f;
#pragma unroll
        for (int rg = 0; rg < 4; rg++) {
            float kf[16];
            const __half2* h0 = (const __half2*)&kv[rg][0];
            const __half2* h1 = (const __half2*)&kv[rg][1];
#pragma unroll
            for (int q = 0; q < 4; q++) {
                float2 f = __half22float2(h0[q]);
                kf[2 * q] = f.x; kf[2 * q + 1] = f.y;
                float2 f2 = __half22float2(h1[q]);
                kf[8 + 2 * q] = f2.x; kf[8 + 2 * q + 1] = f2.y;
            }
            float part = 0.0f;
#pragma unroll
            for (int j = 0; j < 16; j++) part = fmaf(kf[j], e[j], part);
            part += __shfl_xor(part, 8, 64);   // 16-lane tree: 4 rows in parallel
            part += __shfl_xor(part, 4, 64);
            part += __shfl_xor(part, 2, 64);
            part += __shfl_xor(part, 1, 64);
            float ai = MUKS * __builtin_amdgcn_rcpf(part);  // = exp(u_row)
            if (t == N_ITER - 1 && c == 0) aexp[row_base + rg * 4] = ai;
#pragma unroll
            for (int j = 0; j < 16; j++) acc[j] = fmaf(kf[j], ai, acc[j]);
        }
#pragma unroll
        for (int j = 0; j < 16; j++) {
            acc[j] += __shfl_xor(acc[j], 16, 64);
            acc[j] += __shfl_xor(acc[j], 32, 64);
        }
        if (g == 0) {
#pragma unroll
            for (int j = 0; j < 16; j++) cs_lds[w * 273 + c * 17 + j] = acc[j];
        }
        __syncthreads();
        float v = 0.0f;
#pragma unroll
        for (int p = 0; p < 4; p++) v += cs_lds[p * 273 + (tid >> 4) * 17 + (tid & 15)];
        atomicAdd(&csbuf[p_acc * BUFSTRIDE + (blk & (NSHARD - 1)) * 256 + tid], v);
        grid_barrier(bar, t, blk, tid);
    }
    if (blk == 0 && tid == 0) bar[FLAG_IDX] = 1u;  // flushed at kernel end
    if (grid.thread_rank() == 0xFFFFFFF0u) aexp[0] = 0.0f;  // keep cg anchor live
}

// ---------------------------------------------------------------------------
// Gated fallback: round-3's PROVEN per-iteration kernel. If the cooperative
// kernel completed (flag set), every block exits immediately (~2us/launch).
// If the coop launch failed (flag still 0, buffers pristine), these 50
// launches compute the correct result exactly as in round 3.
// ---------------------------------------------------------------------------
__global__ __launch_bounds__(256) void sinkhorn_step_gated(
        const __half* __restrict__ kappa, float* __restrict__ csbuf,
        float* __restrict__ aexp, const unsigned* __restrict__ flag, int t) {
    if (flag[FLAG_IDX] != 0u) return;  // uniform early exit, no barriers crossed
    __shared__ __align__(16) float ev_lds[256];
    __shared__ float cs_lds[4 * 273];
    const int blk = blockIdx.x, tid = threadIdx.x;
    const int w = tid >> 6, lane = tid & 63;
    const int g = lane >> 4, c = lane & 15;
    const int p_read = (t + 2) % 3, p_acc = t % 3, p_zero = (t + 1) % 3;
    {
        const float* cb = csbuf + p_read * BUFSTRIDE;
        float cs = 0.0f;
#pragma unroll
        for (int s = 0; s < NSHARD; s++) cs += cb[s * 256 + tid];
        ev_lds[tid] = NUKS * __builtin_amdgcn_rcpf(cs);
    }
    if (blk < NSHARD) csbuf[p_zero * BUFSTRIDE + blk * 256 + tid] = 0.0f;
    __syncthreads();
    float e[16];
    {
        float4 e0 = *(const float4*)&ev_lds[c * 16 + 0];
        float4 e1 = *(const float4*)&ev_lds[c * 16 + 4];
        float4 e2 = *(const float4*)&ev_lds[c * 16 + 8];
        float4 e3 = *(const float4*)&ev_lds[c * 16 + 12];
        e[0] = e0.x; e[1] = e0.y; e[2] = e0.z; e[3] = e0.w;
        e[4] = e1.x; e[5] = e1.y; e[6] = e1.z; e[7] = e1.w;
        e[8] = e2.x; e[9] = e2.y; e[10] = e2.z; e[11] = e2.w;
        e[12] = e3.x; e[13] = e3.y; e[14] = e3.z; e[15] = e3.w;
    }
    const int row_base = blk * 64 + w * 16 + g;
    const uint4* kb = (const uint4*)kappa;
    uint4 kv[4][2];
#pragma unroll
    for (int rg = 0; rg < 4; rg++) {
        const size_t base = (size_t)(row_base + rg * 4) * 32 + c * 2;
        kv[rg][0] = kb[base];
        kv[rg][1] = kb[base + 1];
    }
    float acc[16];
#pragma unroll
    for (int j = 0; j < 16; j++) acc[j] = 0.0f;
#pragma unroll
    for (int rg = 0; rg < 4; rg++) {
        float kf[16];
        const __half2* h0 = (const __half2*)&kv[rg][0];
        const __half2* h1 = (const __half2*)&kv[rg][1];
#pragma unroll
        for (int q = 0; q < 4; q++) {
            float2 f = __half22float2(h0[q]);
            kf[2 * q] = f.x; kf[2 * q + 1] = f.y;
            float2 f2 = __half22float2(h1[q]);
            kf[8 + 2 * q] = f2.x; kf[8 + 2 * q + 1] = f2.y;
        }
        float part = 0.0f;
#pragma unroll
        for (int j = 0; j < 16; j++) part = fmaf(kf[j], e[j], part);
        part += __shfl_xor(part, 8, 64);
        part += __shfl_xor(part, 4, 64);
        part += __shfl_xor(part, 2, 64);
        part += __shfl_xor(part, 1, 64);
        float ai = MUKS * __builtin_amdgcn_rcpf(part);
        if (t == N_ITER - 1 && c == 0) aexp[row_base + rg * 4] = ai;
#pragma unroll
        for (int j = 0; j < 16; j++) acc[j] = fmaf(kf[j], ai, acc[j]);
    }
#pragma unroll
    for (int j = 0; j < 16; j++) {
        acc[j] += __shfl_xor(acc[j], 16, 64);
        acc[j] += __shfl_xor(acc[j], 32, 64);
    }
    if (g == 0) {
#pragma unroll
        for (int j = 0; j < 16; j++) cs_lds[w * 273 + c * 17 + j] = acc[j];
    }
    __syncthreads();
    float v = 0.0f;
#pragma unroll
    for (int p = 0; p < 4; p++) v += cs_lds[p * 273 + (tid >> 4) * 17 + (tid & 15)];
    atomicAdd(&csbuf[p_acc * BUFSTRIDE + (blk & (NSHARD - 1)) * 256 + tid], v);
}

// ---------------------------------------------------------------------------
// out = sum_{i,k} pi * C * softmax(|coord|),  pi = a_i * ev_k * kappa/KSCALE,
// C recovered as -eps*ln(kappa*INV_KSCALE - 1e-8) (exact inverse of gemm_kc).
// ---------------------------------------------------------------------------
__global__ __launch_bounds__(256) void finalize(
        const __half* __restrict__ kappa, const float* __restrict__ coord,
        const float* __restrict__ aexp, const float* __restrict__ csfin,
        float* __restrict__ out) {
    __shared__ __align__(16) float ev_lds[256];
    __shared__ float wpart[4];
    const int tid = threadIdx.x, wave = tid >> 6, lane = tid & 63;
    {
        float cs = 0.0f;
#pragma unroll
        for (int s = 0; s < NSHARD; s++) cs += csfin[s * 256 + tid];
        ev_lds[tid] = NUKS * __builtin_amdgcn_rcpf(cs);
    }
    __syncthreads();
    float4 ev = *(const float4*)&ev_lds[lane * 4];
    const int row0 = blockIdx.x * 64 + wave * 16;
    float acc = 0.0f;
    for (int r = 0; r < 16; r++) {
        const int row = row0 + r;
        float ai = aexp[row];
        float4 co = *(const float4*)&coord[(size_t)row * 256 + lane * 4];
        float a0 = fabsf(co.x), a1 = fabsf(co.y), a2 = fabsf(co.z), a3 = fabsf(co.w);
        float mx = wave_max(fmaxf(fmaxf(a0, a1), fmaxf(a2, a3)));
        float e0 = __expf(a0 - mx), e1 = __expf(a1 - mx);
        float e2 = __expf(a2 - mx), e3 = __expf(a3 - mx);
        float Z = wave_sum(e0 + e1 + e2 + e3);
        union { uint2 u; __half2 h[2]; } ku;
        ku.u = *(const uint2*)&kappa[(size_t)row * 256 + lane * 4];
        float2 k01 = __half22float2(ku.h[0]), k23 = __half22float2(ku.h[1]);
        float c0 = -0.1f * __logf(k01.x * INV_KSCALE - 1e-8f);
        float c1 = -0.1f * __logf(k01.y * INV_KSCALE - 1e-8f);
        float c2 = -0.1f * __logf(k23.x * INV_KSCALE - 1e-8f);
        float c3 = -0.1f * __logf(k23.y * INV_KSCALE - 1e-8f);
        float s = k01.x * ev.x * c0 * e0 + k01.y * ev.y * c1 * e1 +
                  k23.x * ev.z * c2 * e2 + k23.y * ev.w * c3 * e3;
        acc = fmaf(s, ai * INV_KSCALE * __builtin_amdgcn_rcpf(Z), acc);
    }
    acc = wave_sum(acc);
    if (lane == 0) wpart[wave] = acc;
    __syncthreads();
    if (tid == 0) atomicAdd(out, wpart[0] + wpart[1] + wpart[2] + wpart[3]);
}

extern "C" void kernel_launch(void* const* d_in, const int* in_sizes, int n_in,
                              void* d_out, int out_size, void* d_ws, size_t ws_size,
                              hipStream_t stream) {
    const float* x = (const float*)d_in[0];
    const float* proto = (const float*)d_in[1];
    const float* coord = (const float*)d_in[2];
    float* out = (float*)d_out;
    char* ws = (char*)d_ws;
    // workspace layout (~34.2 MB)
    __half* kappa = (__half*)(ws);                          // 32 MB
    float* yn = (float*)(ws + 33554432);                    // 128 KB
    float* rn = (float*)(ws + 33554432 + 131072);           // 256 KB
    float* aexp = (float*)(ws + 33554432 + 131072 + 262144);            // 256 KB
    float* csbuf = (float*)(ws + 33554432 + 131072 + 262144 + 262144);  // 24 KB
    unsigned* bar = (unsigned*)(ws + 33554432 + 131072 + 262144 + 262144 + 3 * BUFSTRIDE * 4);

    hipLaunchKernelGGL(proto_norm_init, dim3(257), dim3(64), 0, stream, proto, yn, csbuf, bar, out);
    hipLaunchKernelGGL(row_norm, dim3(1024), dim3(256), 0, stream, x, rn);
    hipLaunchKernelGGL(gemm_kc, dim3(1024, 4), dim3(256), 0, stream, x, yn, rn, kappa);
    {
        void* args[4];
        args[0] = (void*)&kappa;
        args[1] = (void*)&csbuf;
        args[2] = (void*)&aexp;
        args[3] = (void*)&bar;
        hipLaunchCooperativeKernel((void*)sinkhorn_persist, dim3(NBLK), dim3(256), args, 0, stream);
    }
    for (int t = 0; t < N_ITER; t++) {
        hipLaunchKernelGGL(sinkhorn_step_gated, dim3(1024), dim3(256), 0, stream,
                           kappa, csbuf, aexp, (const unsigned*)bar, t);
    }
    const float* csfin = csbuf + ((N_ITER - 1) % 3) * BUFSTRIDE;  // parity of t=49
    hipLaunchKernelGGL(finalize, dim3(1024), dim3(256), 0, stream, kappa, coord, aexp, csfin, out);
}

// Round 7
// 537.907 us; speedup vs baseline: 8.6195x; 8.6195x over previous
//
#include <hip/hip_runtime.h>
#include <hip/hip_fp16.h>

#define B_N 65536
#define K_N 256
#define D_N 128
#define N_ITER 50
#define NSHARD 8
#define BUFSTRIDE (NSHARD * K_N)  // 2048 floats per colsum buffer (8 shards x 256)

constexpr float MU_EPS = 1.0f / 65536.0f + 1e-8f;  // exp(log_mu)
constexpr float NU_EPS = 1.0f / 256.0f + 1e-8f;    // exp(log_nu)
constexpr float KSCALE = 8192.0f;                  // keeps fp16 kappa in normal range
constexpr float INV_KSCALE = 1.0f / 8192.0f;
constexpr float NUKS = NU_EPS * KSCALE;
constexpr float MUKS = MU_EPS * KSCALE;

typedef __attribute__((ext_vector_type(8))) short bf16x8;
typedef __attribute__((ext_vector_type(4))) float f32x4;

__device__ __forceinline__ float wave_sum(float v) {
#pragma unroll
    for (int m = 1; m < 64; m <<= 1) v += __shfl_xor(v, m, 64);
    return v;
}
__device__ __forceinline__ float wave_max(float v) {
#pragma unroll
    for (int m = 1; m < 64; m <<= 1) v = fmaxf(v, __shfl_xor(v, m, 64));
    return v;
}

// round-to-nearest-even fp32 -> bf16 bit pattern (as short)
__device__ __forceinline__ short f32_to_bf16(float x) {
    unsigned u = __float_as_uint(x);
    return (short)((u + 0x7FFFu + ((u >> 16) & 1u)) >> 16);
}
__device__ __forceinline__ float bf16_hi_f32(float x) {  // value of bf16(x)
    unsigned u = __float_as_uint(x);
    unsigned r = ((u + 0x7FFFu + ((u >> 16) & 1u)) >> 16) << 16;
    return __uint_as_float(r);
}

// ---------------------------------------------------------------------------
// Blocks 0..255: L2-normalize prototype rows. Block 256: init colsum buffers
// (3-buffer rotation; buf2/shard0 = NUKS so iteration 0 sees exp(v)=1) and
// zero d_out (harness poisons with 0xAA).
// ---------------------------------------------------------------------------
__global__ __launch_bounds__(64) void proto_norm_init(
        const float* __restrict__ proto, float* __restrict__ yn,
        float* __restrict__ csbuf, float* __restrict__ out) {
    const int blk = blockIdx.x;
    const int lane = threadIdx.x;
    if (blk < 256) {
        float2 p = *(const float2*)&proto[blk * 128 + lane * 2];
        float ss = wave_sum(p.x * p.x + p.y * p.y);
        float inv = 1.0f / fmaxf(sqrtf(ss), 1e-12f);
        *(float2*)&yn[blk * 128 + lane * 2] = make_float2(p.x * inv, p.y * inv);
    } else {
        for (int i = lane; i < 3 * BUFSTRIDE; i += 64)
            csbuf[i] = (i >= 2 * BUFSTRIDE && i < 2 * BUFSTRIDE + K_N) ? NUKS : 0.0f;
        if (lane == 0) out[0] = 0.0f;
    }
}

// rn[i] = 1 / max(||x_i||, 1e-12)  (one wave per row, 16 rows per wave)
__global__ __launch_bounds__(256) void row_norm(const float* __restrict__ x,
                                                float* __restrict__ rn) {
    const int tid = threadIdx.x;
    const int wave = tid >> 6, lane = tid & 63;
    const int row0 = blockIdx.x * 64 + wave * 16;
    for (int r = 0; r < 16; r++) {
        const int row = row0 + r;
        float2 p = *(const float2*)&x[(size_t)row * 128 + lane * 2];
        float ss = wave_sum(p.x * p.x + p.y * p.y);
        if (lane == 0) rn[row] = 1.0f / fmaxf(sqrtf(ss), 1e-12f);
    }
}

// ---------------------------------------------------------------------------
// Split-bf16 MFMA GEMM: C[i,k] = 1 - (x_i.yn_k)*rn_i, kappa = fp16 as before.
// x*rn = hi+lo (bf16 each); dot = ah*bh + al*bh + ah*bl (fp32 MFMA acc) ->
// ~2^-16 accuracy, matches fp32 vector GEMM to well below fp16-kappa noise.
// Block: 256 thr = 4 waves; block covers 64 rows x 256 cols. Wave w owns cols
// [w*64, w*64+64) = 4 col-tiles (B frags register-resident), loops 4 row-tiles.
// Verified layouts (guide §3/m89/m120): A[m=lane&15][k=(lane>>4)*8+j];
// B identical addressing from yn[n][k]; C/D col=lane&15, row=(lane>>4)*4+reg.
// ---------------------------------------------------------------------------
__global__ __launch_bounds__(256, 2) void gemm_mfma(
        const float* __restrict__ x, const float* __restrict__ yn,
        const float* __restrict__ rn, __half* __restrict__ kappa) {
    const int tid = threadIdx.x;
    const int w = tid >> 6, lane = tid & 63;
    const int q = lane >> 4, m = lane & 15;
    const int row0 = blockIdx.x * 64;
    const int colbase = w * 64;
    // B fragments (hi/lo), all 4 col-tiles x 4 k-steps, kept in registers
    bf16x8 bh[4][4], bl[4][4];
#pragma unroll
    for (int ct = 0; ct < 4; ct++) {
        const int col = colbase + ct * 16 + m;
#pragma unroll
        for (int ks = 0; ks < 4; ks++) {
            const float* bp = &yn[col * 128 + ks * 32 + q * 8];
            float4 b0 = *(const float4*)bp;
            float4 b1 = *(const float4*)(bp + 4);
            float bv[8] = {b0.x, b0.y, b0.z, b0.w, b1.x, b1.y, b1.z, b1.w};
#pragma unroll
            for (int j = 0; j < 8; j++) {
                float hi = bf16_hi_f32(bv[j]);
                bh[ct][ks][j] = f32_to_bf16(bv[j]);
                bl[ct][ks][j] = f32_to_bf16(bv[j] - hi);
            }
        }
    }
#pragma unroll
    for (int rt = 0; rt < 4; rt++) {
        const int arow = row0 + rt * 16 + m;
        const float rnv = rn[arow];
        bf16x8 ah[4], al[4];
#pragma unroll
        for (int ks = 0; ks < 4; ks++) {
            const float* ap = &x[(size_t)arow * 128 + ks * 32 + q * 8];
            float4 a0 = *(const float4*)ap;
            float4 a1 = *(const float4*)(ap + 4);
            float av[8] = {a0.x, a0.y, a0.z, a0.w, a1.x, a1.y, a1.z, a1.w};
#pragma unroll
            for (int j = 0; j < 8; j++) {
                float v = av[j] * rnv;
                float hi = bf16_hi_f32(v);
                ah[ks][j] = f32_to_bf16(v);
                al[ks][j] = f32_to_bf16(v - hi);
            }
        }
        f32x4 acc[4];
#pragma unroll
        for (int ct = 0; ct < 4; ct++) acc[ct] = (f32x4){0.f, 0.f, 0.f, 0.f};
#pragma unroll
        for (int ks = 0; ks < 4; ks++) {
#pragma unroll
            for (int ct = 0; ct < 4; ct++) {
                acc[ct] = __builtin_amdgcn_mfma_f32_16x16x32_bf16(ah[ks], bh[ct][ks], acc[ct], 0, 0, 0);
                acc[ct] = __builtin_amdgcn_mfma_f32_16x16x32_bf16(al[ks], bh[ct][ks], acc[ct], 0, 0, 0);
                acc[ct] = __builtin_amdgcn_mfma_f32_16x16x32_bf16(ah[ks], bl[ct][ks], acc[ct], 0, 0, 0);
            }
        }
        // epilogue: C/D map col=m, row=q*4+r; 16 lanes -> 32B contiguous runs
#pragma unroll
        for (int ct = 0; ct < 4; ct++) {
            const int ocol = colbase + ct * 16 + m;
#pragma unroll
            for (int r = 0; r < 4; r++) {
                const int orow = row0 + rt * 16 + q * 4 + r;
                float Cv = 1.0f - acc[ct][r];
                kappa[(size_t)orow * 256 + ocol] =
                    __float2half(KSCALE * (__expf(-10.0f * Cv) + 1e-8f));
            }
        }
    }
}

// ---------------------------------------------------------------------------
// ONE Sinkhorn iteration per launch (round-3 proven kernel; kappa loads
// hoisted above the colsum preamble so L2 latency overlaps IC latency).
// 3-buffer colsum rotation: read (t+2)%3, accumulate t%3, zero (t+1)%3.
// ---------------------------------------------------------------------------
__global__ __launch_bounds__(256) void sinkhorn_step(
        const __half* __restrict__ kappa, float* __restrict__ csbuf,
        float* __restrict__ aexp, int t) {
    __shared__ __align__(16) float ev_lds[256];
    __shared__ float cs_lds[4 * 273];  // [wave][chunk*17 + j] — stride-17, conflict-free
    const int blk = blockIdx.x, tid = threadIdx.x;
    const int w = tid >> 6, lane = tid & 63;
    const int g = lane >> 4, c = lane & 15;
    const int row_base = blk * 64 + w * 16 + g;  // + rg*4
    const uint4* kb = (const uint4*)kappa;       // 8 halves per uint4; row = 32 uint4
    uint4 kv[4][2];
#pragma unroll
    for (int rg = 0; rg < 4; rg++) {             // issue kappa loads FIRST
        const size_t base = (size_t)(row_base + rg * 4) * 32 + c * 2;
        kv[rg][0] = kb[base];
        kv[rg][1] = kb[base + 1];
    }
    const int p_read = (t + 2) % 3, p_acc = t % 3, p_zero = (t + 1) % 3;
    {   // ev_k = NUKS / colsum_k  (thread tid owns column tid)
        const float* cb = csbuf + p_read * BUFSTRIDE;
        float cs = 0.0f;
#pragma unroll
        for (int s = 0; s < NSHARD; s++) cs += cb[s * 256 + tid];
        ev_lds[tid] = NUKS * __builtin_amdgcn_rcpf(cs);
    }
    if (blk < NSHARD) csbuf[p_zero * BUFSTRIDE + blk * 256 + tid] = 0.0f;
    __syncthreads();
    float e[16];
    {
        float4 e0 = *(const float4*)&ev_lds[c * 16 + 0];
        float4 e1 = *(const float4*)&ev_lds[c * 16 + 4];
        float4 e2 = *(const float4*)&ev_lds[c * 16 + 8];
        float4 e3 = *(const float4*)&ev_lds[c * 16 + 12];
        e[0] = e0.x; e[1] = e0.y; e[2] = e0.z; e[3] = e0.w;
        e[4] = e1.x; e[5] = e1.y; e[6] = e1.z; e[7] = e1.w;
        e[8] = e2.x; e[9] = e2.y; e[10] = e2.z; e[11] = e2.w;
        e[12] = e3.x; e[13] = e3.y; e[14] = e3.z; e[15] = e3.w;
    }
    float acc[16];
#pragma unroll
    for (int j = 0; j < 16; j++) acc[j] = 0.0f;
#pragma unroll
    for (int rg = 0; rg < 4; rg++) {
        float kf[16];
        const __half2* h0 = (const __half2*)&kv[rg][0];
        const __half2* h1 = (const __half2*)&kv[rg][1];
#pragma unroll
        for (int qq = 0; qq < 4; qq++) {
            float2 f = __half22float2(h0[qq]);
            kf[2 * qq] = f.x; kf[2 * qq + 1] = f.y;
            float2 f2 = __half22float2(h1[qq]);
            kf[8 + 2 * qq] = f2.x; kf[8 + 2 * qq + 1] = f2.y;
        }
        float part = 0.0f;
#pragma unroll
        for (int j = 0; j < 16; j++) part = fmaf(kf[j], e[j], part);
        part += __shfl_xor(part, 8, 64);   // 16-lane tree: 4 rows in parallel
        part += __shfl_xor(part, 4, 64);
        part += __shfl_xor(part, 2, 64);
        part += __shfl_xor(part, 1, 64);
        float ai = MUKS * __builtin_amdgcn_rcpf(part);  // = exp(u_row)
        if (t == N_ITER - 1 && c == 0) aexp[row_base + rg * 4] = ai;
#pragma unroll
        for (int j = 0; j < 16; j++) acc[j] = fmaf(kf[j], ai, acc[j]);
    }
#pragma unroll
    for (int j = 0; j < 16; j++) {
        acc[j] += __shfl_xor(acc[j], 16, 64);
        acc[j] += __shfl_xor(acc[j], 32, 64);
    }
    if (g == 0) {
#pragma unroll
        for (int j = 0; j < 16; j++) cs_lds[w * 273 + c * 17 + j] = acc[j];
    }
    __syncthreads();
    float v = 0.0f;
#pragma unroll
    for (int p = 0; p < 4; p++) v += cs_lds[p * 273 + (tid >> 4) * 17 + (tid & 15)];
    atomicAdd(&csbuf[p_acc * BUFSTRIDE + (blk & (NSHARD - 1)) * 256 + tid], v);
}

// ---------------------------------------------------------------------------
// out = sum_{i,k} pi * C * softmax(|coord|),  pi = a_i * ev_k * kappa/KSCALE,
// C recovered as -eps*ln(kappa*INV_KSCALE - 1e-8) (exact inverse of gemm).
// ---------------------------------------------------------------------------
__global__ __launch_bounds__(256) void finalize(
        const __half* __restrict__ kappa, const float* __restrict__ coord,
        const float* __restrict__ aexp, const float* __restrict__ csfin,
        float* __restrict__ out) {
    __shared__ __align__(16) float ev_lds[256];
    __shared__ float wpart[4];
    const int tid = threadIdx.x, wave = tid >> 6, lane = tid & 63;
    {
        float cs = 0.0f;
#pragma unroll
        for (int s = 0; s < NSHARD; s++) cs += csfin[s * 256 + tid];
        ev_lds[tid] = NUKS * __builtin_amdgcn_rcpf(cs);
    }
    __syncthreads();
    float4 ev = *(const float4*)&ev_lds[lane * 4];
    const int row0 = blockIdx.x * 64 + wave * 16;
    float acc = 0.0f;
    for (int r = 0; r < 16; r++) {
        const int row = row0 + r;
        float ai = aexp[row];
        float4 co = *(const float4*)&coord[(size_t)row * 256 + lane * 4];
        float a0 = fabsf(co.x), a1 = fabsf(co.y), a2 = fabsf(co.z), a3 = fabsf(co.w);
        float mx = wave_max(fmaxf(fmaxf(a0, a1), fmaxf(a2, a3)));
        float e0 = __expf(a0 - mx), e1 = __expf(a1 - mx);
        float e2 = __expf(a2 - mx), e3 = __expf(a3 - mx);
        float Z = wave_sum(e0 + e1 + e2 + e3);
        union { uint2 u; __half2 h[2]; } ku;
        ku.u = *(const uint2*)&kappa[(size_t)row * 256 + lane * 4];
        float2 k01 = __half22float2(ku.h[0]), k23 = __half22float2(ku.h[1]);
        float c0 = -0.1f * __logf(k01.x * INV_KSCALE - 1e-8f);
        float c1 = -0.1f * __logf(k01.y * INV_KSCALE - 1e-8f);
        float c2 = -0.1f * __logf(k23.x * INV_KSCALE - 1e-8f);
        float c3 = -0.1f * __logf(k23.y * INV_KSCALE - 1e-8f);
        float s = k01.x * ev.x * c0 * e0 + k01.y * ev.y * c1 * e1 +
                  k23.x * ev.z * c2 * e2 + k23.y * ev.w * c3 * e3;
        acc = fmaf(s, ai * INV_KSCALE * __builtin_amdgcn_rcpf(Z), acc);
    }
    acc = wave_sum(acc);
    if (lane == 0) wpart[wave] = acc;
    __syncthreads();
    if (tid == 0) atomicAdd(out, wpart[0] + wpart[1] + wpart[2] + wpart[3]);
}

extern "C" void kernel_launch(void* const* d_in, const int* in_sizes, int n_in,
                              void* d_out, int out_size, void* d_ws, size_t ws_size,
                              hipStream_t stream) {
    const float* x = (const float*)d_in[0];
    const float* proto = (const float*)d_in[1];
    const float* coord = (const float*)d_in[2];
    float* out = (float*)d_out;
    char* ws = (char*)d_ws;
    // workspace layout (~34.2 MB)
    __half* kappa = (__half*)(ws);                          // 32 MB
    float* yn = (float*)(ws + 33554432);                    // 128 KB
    float* rn = (float*)(ws + 33554432 + 131072);           // 256 KB
    float* aexp = (float*)(ws + 33554432 + 131072 + 262144);            // 256 KB
    float* csbuf = (float*)(ws + 33554432 + 131072 + 262144 + 262144);  // 24 KB

    hipLaunchKernelGGL(proto_norm_init, dim3(257), dim3(64), 0, stream, proto, yn, csbuf, out);
    hipLaunchKernelGGL(row_norm, dim3(1024), dim3(256), 0, stream, x, rn);
    hipLaunchKernelGGL(gemm_mfma, dim3(1024), dim3(256), 0, stream, x, yn, rn, kappa);
    for (int t = 0; t < N_ITER; t++) {
        hipLaunchKernelGGL(sinkhorn_step, dim3(1024), dim3(256), 0, stream,
                           kappa, csbuf, aexp, t);
    }
    const float* csfin = csbuf + ((N_ITER - 1) % 3) * BUFSTRIDE;  // parity of t=49
    hipLaunchKernelGGL(finalize, dim3(1024), dim3(256), 0, stream, kappa, coord, aexp, csfin, out);
}